// Round 2
// baseline (297.245 us; speedup 1.0000x reference)
//
#include <hip/hip_runtime.h>
#include <stdint.h>

typedef float fv4 __attribute__((ext_vector_type(4)));
typedef int   iv4 __attribute__((ext_vector_type(4)));
typedef short sv4 __attribute__((ext_vector_type(4)));
typedef short sv8 __attribute__((ext_vector_type(8)));

__device__ __forceinline__ short f2bf(float f) {
  uint32_t u = __builtin_bit_cast(uint32_t, f);
  u += 0x7FFFu + ((u >> 16) & 1u);
  return (short)(u >> 16);
}

__device__ __forceinline__ float redmax16(float v) {
#pragma unroll
  for (int m = 1; m < 16; m <<= 1) v = fmaxf(v, __shfl_xor(v, m));
  return v;
}
__device__ __forceinline__ float redsum16(float v) {
#pragma unroll
  for (int m = 1; m < 16; m <<= 1) v += __shfl_xor(v, m);
  return v;
}

// ---------------- fp32 -> bf16 convert ----------------
__global__ __launch_bounds__(256) void f2bf_k(const float* __restrict__ src,
                                              short* __restrict__ dst, int n) {
  int i = (blockIdx.x * 256 + threadIdx.x) * 4;
  if (i >= n) return;
  fv4 v = *(const fv4*)(src + i);
  sv4 o;
  o[0] = f2bf(v[0]); o[1] = f2bf(v[1]); o[2] = f2bf(v[2]); o[3] = f2bf(v[3]);
  *(sv4*)(dst + i) = o;
}

// ---------------- GEMM: C[4096][1024] = A[4096][1024] * B[1024][1024]^T ----------------
// A,B bf16 row-major (K contiguous), C fp32. Tile 128x128, BK=64, 4 waves (2x2 of 64x64).
// LDS rows padded 64->72 shorts (144B = 9*16B): 16B-aligned b128 reads, ~2-way banks.
__global__ __launch_bounds__(256) void gemm_bt(const short* __restrict__ A,
                                               const short* __restrict__ B,
                                               float* __restrict__ C) {
  __shared__ short As[128][72];
  __shared__ short Bs[128][72];
  const int tid = threadIdx.x;
  const int lane = tid & 63, wid = tid >> 6;
  const int l16 = lane & 15, grp = lane >> 4;
  const int bm = blockIdx.y * 128, bn = blockIdx.x * 128;
  const int wr = (wid >> 1) * 64, wc = (wid & 1) * 64;
  fv4 acc[4][4] = {};
  for (int ks = 0; ks < 1024; ks += 64) {
    __syncthreads();
#pragma unroll
    for (int c = 0; c < 4; ++c) {
      int idx = tid + c * 256;
      int row = idx >> 3, col = (idx & 7) * 8;
      *(iv4*)&As[row][col] = *(const iv4*)(A + (size_t)(bm + row) * 1024 + ks + col);
      *(iv4*)&Bs[row][col] = *(const iv4*)(B + (size_t)(bn + row) * 1024 + ks + col);
    }
    __syncthreads();
#pragma unroll
    for (int kk = 0; kk < 2; ++kk) {
      sv8 a[4], b[4];
#pragma unroll
      for (int mi = 0; mi < 4; ++mi)
        a[mi] = *(const sv8*)&As[wr + mi * 16 + l16][kk * 32 + grp * 8];
#pragma unroll
      for (int ni = 0; ni < 4; ++ni)
        b[ni] = *(const sv8*)&Bs[wc + ni * 16 + l16][kk * 32 + grp * 8];
#pragma unroll
      for (int mi = 0; mi < 4; ++mi)
#pragma unroll
        for (int ni = 0; ni < 4; ++ni)
          acc[mi][ni] = __builtin_amdgcn_mfma_f32_16x16x32_bf16(a[mi], b[ni], acc[mi][ni], 0, 0, 0);
    }
  }
  // D layout (m89/m91): col = lane&15, row = (lane>>4)*4 + reg
#pragma unroll
  for (int mi = 0; mi < 4; ++mi)
#pragma unroll
    for (int ni = 0; ni < 4; ++ni)
#pragma unroll
      for (int r = 0; r < 4; ++r)
        C[(size_t)(bm + wr + mi * 16 + grp * 4 + r) * 1024 + bn + wc + ni * 16 + l16] =
            acc[mi][ni][r];
}

// ---------------- depthwise conv (window 3, zero pad) + optional RoPE ----------------
// y fp32 [bc*1024+w][1024] -> out bf16 [(bc*8+h)*1024+w][128]
template <bool ROPE>
__global__ __launch_bounds__(256) void conv_rope_k(const float* __restrict__ y,
                                                   const float* __restrict__ ck,
                                                   const float* __restrict__ invf,
                                                   short* __restrict__ out) {
  int id = blockIdx.x * 256 + threadIdx.x;
  int g8 = id & 127;
  int w = (id >> 7) & 1023;
  int bc = id >> 17;
  int g0 = g8 << 3;
  const float* row = y + ((size_t)(bc * 1024 + w)) * 1024 + g0;
  float a[8];
  {
    fv4 v0 = *(const fv4*)(row);
    fv4 v1 = *(const fv4*)(row + 4);
    fv4 c0 = *(const fv4*)(ck + 1024 + g0);
    fv4 c1 = *(const fv4*)(ck + 1024 + g0 + 4);
#pragma unroll
    for (int j = 0; j < 4; ++j) { a[j] = v0[j] * c0[j]; a[4 + j] = v1[j] * c1[j]; }
  }
  if (w > 0) {
    fv4 v0 = *(const fv4*)(row - 1024);
    fv4 v1 = *(const fv4*)(row - 1024 + 4);
    fv4 c0 = *(const fv4*)(ck + g0);
    fv4 c1 = *(const fv4*)(ck + g0 + 4);
#pragma unroll
    for (int j = 0; j < 4; ++j) { a[j] += v0[j] * c0[j]; a[4 + j] += v1[j] * c1[j]; }
  }
  if (w < 1023) {
    fv4 v0 = *(const fv4*)(row + 1024);
    fv4 v1 = *(const fv4*)(row + 1024 + 4);
    fv4 c0 = *(const fv4*)(ck + 2048 + g0);
    fv4 c1 = *(const fv4*)(ck + 2048 + g0 + 4);
#pragma unroll
    for (int j = 0; j < 4; ++j) { a[j] += v0[j] * c0[j]; a[4 + j] += v1[j] * c1[j]; }
  }
  int d0 = g0 & 127;
  if (ROPE) {
    if (d0 < 64) {
#pragma unroll
      for (int jj = 0; jj < 4; ++jj) {
        int fi = (d0 >> 1) + jj;
        float th = (float)w * invf[fi];
        float sn = sinf(th), cs = cosf(th);
        float e0 = a[2 * jj], e1 = a[2 * jj + 1];
        a[2 * jj] = e0 * cs - e1 * sn;
        a[2 * jj + 1] = e1 * cs + e0 * sn;
      }
    }
  }
  int h = g0 >> 7;
  sv8 o;
#pragma unroll
  for (int j = 0; j < 8; ++j) o[j] = f2bf(a[j]);
  *(sv8*)(out + ((size_t)((bc * 8 + h) * 1024 + w)) * 128 + d0) = o;
}

// ---------------- flash attention: 32 (b,c,h) problems of [1024 x 128] ----------------
// Block: 256 thr = 4 waves, each wave owns 32 q rows (block 128), KB=32 keys/iter.
__global__ __launch_bounds__(256) void attn_k(const short* __restrict__ Q,
                                              const short* __restrict__ K,
                                              const short* __restrict__ V,
                                              short* __restrict__ O) {
  __shared__ short Ks[32][136];   // keys row-major, padded
  __shared__ short Vt[128][36];   // V transposed [d][key], padded
  __shared__ short Ps[4][32][36]; // per-wave P tile [q][key], padded
  const int tid = threadIdx.x, lane = tid & 63, wid = tid >> 6;
  const int l16 = lane & 15, grp = lane >> 4;
  const int bch = blockIdx.x, qb = blockIdx.y;
  const size_t base = (size_t)bch * 1024 * 128;
  const short* Qb = Q + base;
  const short* Kb = K + base;
  const short* Vb = V + base;
  const int q0 = qb * 128 + wid * 32;
  sv8 qf[2][4];
#pragma unroll
  for (int mi = 0; mi < 2; ++mi)
#pragma unroll
    for (int kk = 0; kk < 4; ++kk)
      qf[mi][kk] = *(const sv8*)(Qb + (size_t)(q0 + mi * 16 + l16) * 128 + kk * 32 + grp * 8);
  fv4 o[2][8] = {};
  float m[2][4], l[2][4];
#pragma unroll
  for (int mi = 0; mi < 2; ++mi)
#pragma unroll
    for (int r = 0; r < 4; ++r) { m[mi][r] = -1e30f; l[mi][r] = 0.f; }

  for (int kb = 0; kb < 1024; kb += 32) {
    __syncthreads();
#pragma unroll
    for (int c = 0; c < 2; ++c) {
      int idx = tid + c * 256;
      int r = idx >> 4, col = (idx & 15) * 8;
      *(iv4*)&Ks[r][col] = *(const iv4*)(Kb + (size_t)(kb + r) * 128 + col);
      sv8 vv = *(const sv8*)(Vb + (size_t)(kb + r) * 128 + col);
#pragma unroll
      for (int j = 0; j < 8; ++j) Vt[col + j][r] = vv[j];
    }
    __syncthreads();
#pragma unroll
    for (int mi = 0; mi < 2; ++mi) {
      fv4 s0 = {}, s1 = {};
#pragma unroll
      for (int kk = 0; kk < 4; ++kk) {
        sv8 k0 = *(const sv8*)&Ks[l16][kk * 32 + grp * 8];
        sv8 k1 = *(const sv8*)&Ks[16 + l16][kk * 32 + grp * 8];
        s0 = __builtin_amdgcn_mfma_f32_16x16x32_bf16(qf[mi][kk], k0, s0, 0, 0, 0);
        s1 = __builtin_amdgcn_mfma_f32_16x16x32_bf16(qf[mi][kk], k1, s1, 0, 0, 0);
      }
      const float sc = 0.03125f; // 1/sqrt(1024)
      float cor[4];
#pragma unroll
      for (int r = 0; r < 4; ++r) {
        s0[r] *= sc; s1[r] *= sc;
        float v = redmax16(fmaxf(s0[r], s1[r]));
        float mn = fmaxf(m[mi][r], v);
        cor[r] = __expf(m[mi][r] - mn);
        m[mi][r] = mn;
        s0[r] = __expf(s0[r] - mn);
        s1[r] = __expf(s1[r] - mn);
        float rs = redsum16(s0[r] + s1[r]);
        l[mi][r] = l[mi][r] * cor[r] + rs;
        Ps[wid][mi * 16 + grp * 4 + r][l16] = f2bf(s0[r]);
        Ps[wid][mi * 16 + grp * 4 + r][16 + l16] = f2bf(s1[r]);
      }
#pragma unroll
      for (int db = 0; db < 8; ++db)
#pragma unroll
        for (int r = 0; r < 4; ++r) o[mi][db][r] *= cor[r];
    }
    // PV: O[q][d] += P[q][key] * V[key][d]
#pragma unroll
    for (int mi = 0; mi < 2; ++mi) {
      sv4 plo = *(const sv4*)&Ps[wid][mi * 16 + l16][grp * 8];
      sv4 phi = *(const sv4*)&Ps[wid][mi * 16 + l16][grp * 8 + 4];
      sv8 pa;
#pragma unroll
      for (int j = 0; j < 4; ++j) { pa[j] = plo[j]; pa[4 + j] = phi[j]; }
#pragma unroll
      for (int db = 0; db < 8; ++db) {
        sv4 vlo = *(const sv4*)&Vt[db * 16 + l16][grp * 8];
        sv4 vhi = *(const sv4*)&Vt[db * 16 + l16][grp * 8 + 4];
        sv8 vf;
#pragma unroll
        for (int j = 0; j < 4; ++j) { vf[j] = vlo[j]; vf[4 + j] = vhi[j]; }
        o[mi][db] = __builtin_amdgcn_mfma_f32_16x16x32_bf16(pa, vf, o[mi][db], 0, 0, 0);
      }
    }
  }
  const int bc = bch >> 3, h = bch & 7;
#pragma unroll
  for (int mi = 0; mi < 2; ++mi) {
    float inv[4];
#pragma unroll
    for (int r = 0; r < 4; ++r) inv[r] = 1.0f / l[mi][r];
#pragma unroll
    for (int db = 0; db < 8; ++db)
#pragma unroll
      for (int r = 0; r < 4; ++r) {
        int q = q0 + mi * 16 + grp * 4 + r;
        O[((size_t)(bc * 1024 + q)) * 1024 + h * 128 + db * 16 + l16] =
            f2bf(o[mi][db][r] * inv[r]);
      }
  }
}

extern "C" void kernel_launch(void* const* d_in, const int* in_sizes, int n_in,
                              void* d_out, int out_size, void* d_ws, size_t ws_size,
                              hipStream_t stream) {
  const float* x = (const float*)d_in[0];
  const float* q_w = (const float*)d_in[1];
  const float* q_conv = (const float*)d_in[2];
  const float* k_w = (const float*)d_in[3];
  const float* k_conv = (const float*)d_in[4];
  const float* v_w = (const float*)d_in[5];
  const float* v_conv = (const float*)d_in[6];
  const float* out_w = (const float*)d_in[7];
  const float* inv_freq = (const float*)d_in[8];

  char* ws = (char*)d_ws;
  short* x_bf  = (short*)(ws);              // 8,388,608 B
  short* qw_bf = (short*)(ws + 8388608);    // 2,097,152 B
  short* kw_bf = (short*)(ws + 10485760);
  short* vw_bf = (short*)(ws + 12582912);
  short* ow_bf = (short*)(ws + 14680064);
  float* y_buf = (float*)(ws + 16777216);   // 16,777,216 B (reused q/k/v serially)
  short* q_h   = (short*)(ws + 33554432);   // 8,388,608 B each
  short* k_h   = (short*)(ws + 41943040);
  short* v_h   = (short*)(ws + 50331648);
  short* o_flat= (short*)(ws + 58720256);   // ends at 67,108,864

  f2bf_k<<<4096, 256, 0, stream>>>(x, x_bf, 4194304);
  f2bf_k<<<1024, 256, 0, stream>>>(q_w, qw_bf, 1048576);
  f2bf_k<<<1024, 256, 0, stream>>>(k_w, kw_bf, 1048576);
  f2bf_k<<<1024, 256, 0, stream>>>(v_w, vw_bf, 1048576);
  f2bf_k<<<1024, 256, 0, stream>>>(out_w, ow_bf, 1048576);

  dim3 gg(8, 32); // (N/128, M/128)
  gemm_bt<<<gg, 256, 0, stream>>>(x_bf, qw_bf, y_buf);
  conv_rope_k<true><<<2048, 256, 0, stream>>>(y_buf, q_conv, inv_freq, q_h);
  gemm_bt<<<gg, 256, 0, stream>>>(x_bf, kw_bf, y_buf);
  conv_rope_k<true><<<2048, 256, 0, stream>>>(y_buf, k_conv, inv_freq, k_h);
  gemm_bt<<<gg, 256, 0, stream>>>(x_bf, vw_bf, y_buf);
  conv_rope_k<false><<<2048, 256, 0, stream>>>(y_buf, v_conv, inv_freq, v_h);

  attn_k<<<dim3(32, 8), 256, 0, stream>>>(q_h, k_h, v_h, o_flat);

  gemm_bt<<<gg, 256, 0, stream>>>(o_flat, ow_bf, (float*)d_out);
}

// Round 7
// 233.369 us; speedup vs baseline: 1.2737x; 1.2737x over previous
//
#include <hip/hip_runtime.h>
#include <stdint.h>

typedef float fv4 __attribute__((ext_vector_type(4)));
typedef float fv2 __attribute__((ext_vector_type(2)));
typedef int   iv4 __attribute__((ext_vector_type(4)));
typedef short sv4 __attribute__((ext_vector_type(4)));
typedef short sv8 __attribute__((ext_vector_type(8)));

__device__ __forceinline__ short f2bf(float f) {
  uint32_t u = __builtin_bit_cast(uint32_t, f);
  u += 0x7FFFu + ((u >> 16) & 1u);
  return (short)(u >> 16);
}
__device__ __forceinline__ float bf2f(short s) {
  uint32_t u = ((uint32_t)(uint16_t)s) << 16;
  return __builtin_bit_cast(float, u);
}
__device__ __forceinline__ float redmax16(float v) {
#pragma unroll
  for (int m = 1; m < 16; m <<= 1) v = fmaxf(v, __shfl_xor(v, m));
  return v;
}
__device__ __forceinline__ float redsum16(float v) {
#pragma unroll
  for (int m = 1; m < 16; m <<= 1) v += __shfl_xor(v, m);
  return v;
}
__device__ __forceinline__ void gload_lds16(const void* g, void* l) {
  __builtin_amdgcn_global_load_lds((const __attribute__((address_space(1))) void*)g,
                                   (__attribute__((address_space(3))) void*)l, 16, 0, 0);
}

// ---------------- fp32 -> bf16 convert (x) ----------------
__global__ __launch_bounds__(256) void f2bf_k(const float* __restrict__ src,
                                              short* __restrict__ dst) {
  int i = (blockIdx.x * 256 + threadIdx.x) * 4;
  fv4 v = *(const fv4*)(src + i);
  sv4 o;
  o[0] = f2bf(v[0]); o[1] = f2bf(v[1]); o[2] = f2bf(v[2]); o[3] = f2bf(v[3]);
  *(sv4*)(dst + i) = o;
}

// ---------------- 4 weight matrices -> contiguous bf16 ----------------
__global__ __launch_bounds__(256) void w4_k(const float* __restrict__ s0,
                                            const float* __restrict__ s1,
                                            const float* __restrict__ s2,
                                            const float* __restrict__ s3,
                                            short* __restrict__ dst) {
  int p = blockIdx.x >> 10;
  const float* s = p == 0 ? s0 : (p == 1 ? s1 : (p == 2 ? s2 : s3));
  int i = ((blockIdx.x & 1023) * 256 + threadIdx.x) * 4;
  fv4 v = *(const fv4*)(s + i);
  sv4 o;
  o[0] = f2bf(v[0]); o[1] = f2bf(v[1]); o[2] = f2bf(v[2]); o[3] = f2bf(v[3]);
  *(sv4*)(dst + (size_t)p * 1048576 + i) = o;
}

// ---------------- RoPE cos/sin table: tab[w][32] = (cos, sin) ----------------
__global__ __launch_bounds__(256) void ropetab_k(const float* __restrict__ invf,
                                                 fv2* __restrict__ tab) {
  int id = blockIdx.x * 256 + threadIdx.x; // 32768
  int w = id >> 5, fi = id & 31;
  float th = (float)w * invf[fi];
  fv2 cs; cs[0] = cosf(th); cs[1] = sinf(th);
  tab[id] = cs;
}

// ---------------- GEMM: C[4096][1024] = A[4096][1024] * B[1024][1024]^T ----------------
// m97 structure: linear LDS [128][64], global_load_lds width=16, 2-barrier loop.
// proj = blockIdx.x>>3 selects B (+proj*1M shorts) and C (+proj*4M elems) for fused QKV.
template <typename CT>
__global__ __launch_bounds__(256, 3) void gemm_bt(const short* __restrict__ A,
                                                  const short* __restrict__ B,
                                                  CT* __restrict__ C) {
  __shared__ short As[128 * 64];
  __shared__ short Bs[128 * 64];
  const int tid = threadIdx.x, lane = tid & 63, wid = tid >> 6;
  const int l16 = lane & 15, grp = lane >> 4;
  const int proj = blockIdx.x >> 3;
  const int bn = (blockIdx.x & 7) * 128;
  const int bm = blockIdx.y * 128;
  const short* Bp = B + (size_t)proj * 1048576;
  CT* Cp = C + (size_t)proj * 4194304;
  const int wr = (wid >> 1) * 64, wc = (wid & 1) * 64;
  fv4 acc[4][4] = {};
  // lane-row mapping for staging: chunk covers rows [chunk*8, chunk*8+8)
  const int srow = lane >> 3, scol = (lane & 7) * 8;
  for (int ks = 0; ks < 1024; ks += 64) {
    __syncthreads();
#pragma unroll
    for (int c = 0; c < 4; ++c) {
      int chunk = c * 4 + wid;
      gload_lds16(A + (size_t)(bm + chunk * 8 + srow) * 1024 + ks + scol, As + chunk * 512);
      gload_lds16(Bp + (size_t)(bn + chunk * 8 + srow) * 1024 + ks + scol, Bs + chunk * 512);
    }
    asm volatile("s_waitcnt vmcnt(0)" ::: "memory");
    __syncthreads();
#pragma unroll
    for (int kk = 0; kk < 2; ++kk) {
      sv8 a[4], b[4];
#pragma unroll
      for (int mi = 0; mi < 4; ++mi)
        a[mi] = *(const sv8*)&As[(wr + mi * 16 + l16) * 64 + kk * 32 + grp * 8];
#pragma unroll
      for (int ni = 0; ni < 4; ++ni)
        b[ni] = *(const sv8*)&Bs[(wc + ni * 16 + l16) * 64 + kk * 32 + grp * 8];
#pragma unroll
      for (int mi = 0; mi < 4; ++mi)
#pragma unroll
        for (int ni = 0; ni < 4; ++ni)
          acc[mi][ni] = __builtin_amdgcn_mfma_f32_16x16x32_bf16(a[mi], b[ni], acc[mi][ni], 0, 0, 0);
    }
  }
#pragma unroll
  for (int mi = 0; mi < 4; ++mi)
#pragma unroll
    for (int ni = 0; ni < 4; ++ni)
#pragma unroll
      for (int r = 0; r < 4; ++r) {
        float v = acc[mi][ni][r];
        CT* p = Cp + (size_t)(bm + wr + mi * 16 + grp * 4 + r) * 1024 + bn + wc + ni * 16 + l16;
        if constexpr (sizeof(CT) == 2) *p = f2bf(v); else *p = v;
      }
}

// ---------------- fused depthwise conv + RoPE (y bf16) ----------------
__global__ __launch_bounds__(256) void conv_rope_k(const short* __restrict__ y3,
                                                   const float* __restrict__ cq,
                                                   const float* __restrict__ ckk,
                                                   const float* __restrict__ cv,
                                                   const fv2* __restrict__ tab,
                                                   short* __restrict__ qh,
                                                   short* __restrict__ kh,
                                                   short* __restrict__ vh) {
  const int proj = blockIdx.y;
  const short* y = y3 + (size_t)proj * 4194304;
  const float* ck = proj == 0 ? cq : (proj == 1 ? ckk : cv);
  short* out = proj == 0 ? qh : (proj == 1 ? kh : vh);
  int id = blockIdx.x * 256 + threadIdx.x;
  int g8 = id & 127, w = (id >> 7) & 1023, bc = id >> 17;
  int g0 = g8 << 3;
  const short* row = y + ((size_t)(bc * 1024 + w)) * 1024 + g0;
  float a[8];
  {
    sv8 v = *(const sv8*)row;
    fv4 c0 = *(const fv4*)(ck + 1024 + g0);
    fv4 c1 = *(const fv4*)(ck + 1024 + g0 + 4);
#pragma unroll
    for (int j = 0; j < 4; ++j) { a[j] = bf2f(v[j]) * c0[j]; a[4 + j] = bf2f(v[4 + j]) * c1[j]; }
  }
  if (w > 0) {
    sv8 v = *(const sv8*)(row - 1024);
    fv4 c0 = *(const fv4*)(ck + g0);
    fv4 c1 = *(const fv4*)(ck + g0 + 4);
#pragma unroll
    for (int j = 0; j < 4; ++j) { a[j] += bf2f(v[j]) * c0[j]; a[4 + j] += bf2f(v[4 + j]) * c1[j]; }
  }
  if (w < 1023) {
    sv8 v = *(const sv8*)(row + 1024);
    fv4 c0 = *(const fv4*)(ck + 2048 + g0);
    fv4 c1 = *(const fv4*)(ck + 2048 + g0 + 4);
#pragma unroll
    for (int j = 0; j < 4; ++j) { a[j] += bf2f(v[j]) * c0[j]; a[4 + j] += bf2f(v[4 + j]) * c1[j]; }
  }
  int d0 = g0 & 127;
  if (proj < 2 && d0 < 64) {
#pragma unroll
    for (int jj = 0; jj < 4; ++jj) {
      fv2 cs = tab[(w << 5) + (d0 >> 1) + jj];
      float e0 = a[2 * jj], e1 = a[2 * jj + 1];
      a[2 * jj] = e0 * cs[0] - e1 * cs[1];
      a[2 * jj + 1] = e1 * cs[0] + e0 * cs[1];
    }
  }
  int h = g0 >> 7;
  sv8 o;
#pragma unroll
  for (int j = 0; j < 8; ++j) o[j] = f2bf(a[j]);
  *(sv8*)(out + ((size_t)((bc * 8 + h) * 1024 + w)) * 128 + d0) = o;
}

// ---------------- V transpose: vh[bch][key][128] -> vt[bch][d][1024] ----------------
__global__ __launch_bounds__(256) void vtrans_k(const short* __restrict__ vh,
                                                short* __restrict__ vt) {
  __shared__ short T[64][136];
  const int bch = blockIdx.x, kt = blockIdx.y;
  const short* src = vh + ((size_t)bch * 1024 + kt * 64) * 128;
#pragma unroll
  for (int c = 0; c < 4; ++c) {
    int idx = c * 2048 + threadIdx.x * 8;
    int r = idx >> 7, col = idx & 127;
    *(sv8*)&T[r][col] = *(const sv8*)(src + (size_t)r * 128 + col);
  }
  __syncthreads();
  const int d = threadIdx.x >> 1, half = threadIdx.x & 1;
  short* dst = vt + (size_t)bch * 131072 + (size_t)d * 1024 + kt * 64 + half * 32;
#pragma unroll
  for (int v = 0; v < 4; ++v) {
    sv8 o;
#pragma unroll
    for (int j = 0; j < 8; ++j) o[j] = T[half * 32 + v * 8 + j][d];
    *(sv8*)(dst + v * 8) = o;
  }
}

// ---------------- flash attention: barrier-free, direct L2 reads ----------------
// grid (32 bch, 8 qb), 256 thr = 4 independent waves, wave = 32 q rows, KB=64.
__global__ __launch_bounds__(256, 1) void attn_k(const short* __restrict__ Q,
                                                 const short* __restrict__ K,
                                                 const short* __restrict__ Vt,
                                                 short* __restrict__ O) {
  __shared__ short Ps[4][32][72]; // per-wave P tile [q][64 keys], 144B rows
  const int tid = threadIdx.x, lane = tid & 63, wid = tid >> 6;
  const int l16 = lane & 15, grp = lane >> 4;
  const int bch = blockIdx.x, qb = blockIdx.y;
  const short* Qb = Q + (size_t)bch * 131072;
  const short* Kb = K + (size_t)bch * 131072;
  const short* Vb = Vt + (size_t)bch * 131072;
  const int q0 = qb * 128 + wid * 32;
  sv8 qf[2][4];
#pragma unroll
  for (int mi = 0; mi < 2; ++mi)
#pragma unroll
    for (int kk = 0; kk < 4; ++kk)
      qf[mi][kk] = *(const sv8*)(Qb + (size_t)(q0 + mi * 16 + l16) * 128 + kk * 32 + grp * 8);
  fv4 o[2][8] = {};
  float m[2][4], l[2][4];
#pragma unroll
  for (int mi = 0; mi < 2; ++mi)
#pragma unroll
    for (int r = 0; r < 4; ++r) { m[mi][r] = -1e30f; l[mi][r] = 0.f; }

  for (int kb = 0; kb < 1024; kb += 64) {
    // QK^T: S[32 q][64 k], K frags direct from global (L2-resident)
    fv4 s[2][4] = {};
    sv8 kf[4][4];
#pragma unroll
    for (int kg = 0; kg < 4; ++kg)
#pragma unroll
      for (int kk = 0; kk < 4; ++kk)
        kf[kg][kk] = *(const sv8*)(Kb + (size_t)(kb + kg * 16 + l16) * 128 + kk * 32 + grp * 8);
#pragma unroll
    for (int kg = 0; kg < 4; ++kg)
#pragma unroll
      for (int kk = 0; kk < 4; ++kk) {
        s[0][kg] = __builtin_amdgcn_mfma_f32_16x16x32_bf16(qf[0][kk], kf[kg][kk], s[0][kg], 0, 0, 0);
        s[1][kg] = __builtin_amdgcn_mfma_f32_16x16x32_bf16(qf[1][kk], kf[kg][kk], s[1][kg], 0, 0, 0);
      }
    // V frags issued early: overlap their L2 latency with softmax VALU
    sv8 vf[8][2];
#pragma unroll
    for (int db = 0; db < 8; ++db)
#pragma unroll
      for (int ks2 = 0; ks2 < 2; ++ks2)
        vf[db][ks2] = *(const sv8*)(Vb + (size_t)(db * 16 + l16) * 1024 + kb + ks2 * 32 + grp * 8);
    // online softmax (rows: q = grp*4+r; cols: k = kg*16+l16)
    const float sc = 0.03125f; // 1/sqrt(1024)
#pragma unroll
    for (int mi = 0; mi < 2; ++mi) {
      float cor[4];
#pragma unroll
      for (int r = 0; r < 4; ++r) {
#pragma unroll
        for (int kg = 0; kg < 4; ++kg) s[mi][kg][r] *= sc;
        float v0 = fmaxf(fmaxf(s[mi][0][r], s[mi][1][r]), fmaxf(s[mi][2][r], s[mi][3][r]));
        v0 = redmax16(v0);
        float mn = fmaxf(m[mi][r], v0);
        cor[r] = __expf(m[mi][r] - mn);
        m[mi][r] = mn;
        float rs = 0.f;
#pragma unroll
        for (int kg = 0; kg < 4; ++kg) {
          float e = __expf(s[mi][kg][r] - mn);
          s[mi][kg][r] = e;
          rs += e;
        }
        rs = redsum16(rs);
        l[mi][r] = l[mi][r] * cor[r] + rs;
#pragma unroll
        for (int kg = 0; kg < 4; ++kg)
          Ps[wid][mi * 16 + grp * 4 + r][kg * 16 + l16] = f2bf(s[mi][kg][r]);
      }
#pragma unroll
      for (int db = 0; db < 8; ++db)
#pragma unroll
        for (int r = 0; r < 4; ++r) o[mi][db][r] *= cor[r];
    }
    // wave-private LDS: drain writes, no __syncthreads needed
    asm volatile("s_waitcnt lgkmcnt(0)" ::: "memory");
    __builtin_amdgcn_sched_barrier(0);
    // PV: O[q][d] += P[q][k] * Vt[d][k]
#pragma unroll
    for (int mi = 0; mi < 2; ++mi) {
      sv8 pa0 = *(const sv8*)&Ps[wid][mi * 16 + l16][grp * 8];
      sv8 pa1 = *(const sv8*)&Ps[wid][mi * 16 + l16][32 + grp * 8];
#pragma unroll
      for (int db = 0; db < 8; ++db) {
        o[mi][db] = __builtin_amdgcn_mfma_f32_16x16x32_bf16(pa0, vf[db][0], o[mi][db], 0, 0, 0);
        o[mi][db] = __builtin_amdgcn_mfma_f32_16x16x32_bf16(pa1, vf[db][1], o[mi][db], 0, 0, 0);
      }
    }
  }
  const int bc = bch >> 3, h = bch & 7;
#pragma unroll
  for (int mi = 0; mi < 2; ++mi) {
    float inv[4];
#pragma unroll
    for (int r = 0; r < 4; ++r) inv[r] = 1.0f / l[mi][r];
#pragma unroll
    for (int db = 0; db < 8; ++db)
#pragma unroll
      for (int r = 0; r < 4; ++r) {
        int q = q0 + mi * 16 + grp * 4 + r;
        O[((size_t)(bc * 1024 + q)) * 1024 + h * 128 + db * 16 + l16] =
            f2bf(o[mi][db][r] * inv[r]);
      }
  }
}

extern "C" void kernel_launch(void* const* d_in, const int* in_sizes, int n_in,
                              void* d_out, int out_size, void* d_ws, size_t ws_size,
                              hipStream_t stream) {
  const float* x = (const float*)d_in[0];
  const float* q_w = (const float*)d_in[1];
  const float* q_conv = (const float*)d_in[2];
  const float* k_w = (const float*)d_in[3];
  const float* k_conv = (const float*)d_in[4];
  const float* v_w = (const float*)d_in[5];
  const float* v_conv = (const float*)d_in[6];
  const float* out_w = (const float*)d_in[7];
  const float* inv_freq = (const float*)d_in[8];

  char* ws = (char*)d_ws;
  short* x_bf = (short*)(ws);                 // [0, 8M)       dead after gemm_qkv
  short* w4   = (short*)(ws + 8388608);       // [8M, 16M)     q|k|v|out bf16, contiguous
  fv2*   tab  = (fv2*)(ws + 16777216);        // [16M, 16.25M)
  short* y3   = (short*)(ws + 17301504);      // [16.5M, 40.5M) bf16 q|k|v projections
  short* q_h  = (short*)(ws);                 // reuse x_bf region
  short* k_h  = (short*)(ws + 42467328);
  short* v_h  = (short*)(ws + 50855936);      // ends 56.5M
  short* v_t  = (short*)(ws + 17301504);      // reuse y[q] region
  short* o_fl = (short*)(ws + 25690112);      // reuse y[k] region

  f2bf_k<<<4096, 256, 0, stream>>>(x, x_bf);
  w4_k<<<4096, 256, 0, stream>>>(q_w, k_w, v_w, out_w, w4);
  ropetab_k<<<128, 256, 0, stream>>>(inv_freq, tab);

  gemm_bt<short><<<dim3(24, 32), 256, 0, stream>>>(x_bf, w4, y3);
  conv_rope_k<<<dim3(2048, 3), 256, 0, stream>>>(y3, q_conv, k_conv, v_conv, tab, q_h, k_h, v_h);
  vtrans_k<<<dim3(32, 16), 256, 0, stream>>>(v_h, v_t);
  attn_k<<<dim3(32, 8), 256, 0, stream>>>(q_h, k_h, v_t, o_fl);
  gemm_bt<float><<<dim3(8, 32), 256, 0, stream>>>(o_fl, w4 + 3145728, (float*)d_out);
}